// Round 1
// 389.496 us; speedup vs baseline: 1.0755x; 1.0755x over previous
//
#include <hip/hip_runtime.h>
#include <hip/hip_bf16.h>

// Problem dims (fixed by the reference)
#define B 64
#define T 2048
#define H 512
#define S 512
#define K 128
#define V 128
#define SPL 32           // splits over T for the fused pass
#define RPB (T / SPL)    // 64 rows per block
#define RPW (RPB / 4)    // 16 rows per wave (4 waves/block)
#define PSTRIDE 516      // per-block partial: 512 ctx + m + l (+2 pad)

// ---------------------------------------------------------------------------
// Kernel A: per-batch prep.
//   query[b,k] = dec[b,:]·Ws[k,:] + bs[k]
//   wq[b,h]    = sum_k query[b,k]*Wh[k,h]
//   c[b]       = sum_k query[b,k]*bh[k]
// ---------------------------------------------------------------------------
__global__ __launch_bounds__(256) void prep_kernel(
    const float* __restrict__ dec, const float* __restrict__ Ws,
    const float* __restrict__ bs, const float* __restrict__ Wh,
    const float* __restrict__ bh, float* __restrict__ wq,
    float* __restrict__ cb) {
  const int b = blockIdx.x;
  const int tid = threadIdx.x;
  __shared__ float s_dec[S];
  __shared__ float s_q[K];

  for (int i = tid; i < S; i += 256) s_dec[i] = dec[b * S + i];
  __syncthreads();

  if (tid < K) {
    const float* w = Ws + (size_t)tid * S;
    // 4 independent accumulators: breaks the serial FMA chain, 4x ILP
    float a0 = 0.f, a1 = 0.f, a2 = 0.f, a3 = 0.f;
    for (int s = 0; s < S; s += 16) {
      const float4 w0 = *(const float4*)(w + s);
      const float4 w1 = *(const float4*)(w + s + 4);
      const float4 w2 = *(const float4*)(w + s + 8);
      const float4 w3 = *(const float4*)(w + s + 12);
      const float4 d0 = *(const float4*)(s_dec + s);
      const float4 d1 = *(const float4*)(s_dec + s + 4);
      const float4 d2 = *(const float4*)(s_dec + s + 8);
      const float4 d3 = *(const float4*)(s_dec + s + 12);
      a0 += w0.x * d0.x + w0.y * d0.y + w0.z * d0.z + w0.w * d0.w;
      a1 += w1.x * d1.x + w1.y * d1.y + w1.z * d1.z + w1.w * d1.w;
      a2 += w2.x * d2.x + w2.y * d2.y + w2.z * d2.z + w2.w * d2.w;
      a3 += w3.x * d3.x + w3.y * d3.y + w3.z * d3.z + w3.w * d3.w;
    }
    s_q[tid] = bs[tid] + ((a0 + a1) + (a2 + a3));
  }
  __syncthreads();

  // cb: wave-parallel reduce instead of serial lane-0 loop
  if (tid < 64) {
    float c = s_q[tid] * bh[tid] + s_q[tid + 64] * bh[tid + 64];
    #pragma unroll
    for (int off = 32; off > 0; off >>= 1) c += __shfl_xor(c, off);
    if (tid == 0) cb[b] = c;
  }

  for (int h = tid; h < H; h += 256) {
    float a0 = 0.f, a1 = 0.f, a2 = 0.f, a3 = 0.f;
    #pragma unroll 8
    for (int k = 0; k < K; k += 4) {
      a0 += s_q[k]     * Wh[(size_t)k * H + h];
      a1 += s_q[k + 1] * Wh[(size_t)(k + 1) * H + h];
      a2 += s_q[k + 2] * Wh[(size_t)(k + 2) * H + h];
      a3 += s_q[k + 3] * Wh[(size_t)(k + 3) * H + h];
    }
    wq[b * H + h] = (a0 + a1) + (a2 + a3);
  }
}

// ---------------------------------------------------------------------------
// Kernel B (fused): single pass over VALID rows of L, online softmax.
// 4 rows per iteration, 4 independent reduce chains (2x the MLP of the old
// 2-row version), energy stored as one aligned float4 per 4 rows.
// Lane holds h = lane*4..+4 and 256+lane*4..+4.
// ---------------------------------------------------------------------------
__global__ __launch_bounds__(256) void fused_kernel(
    const float* __restrict__ L, const float* __restrict__ wq,
    const float* __restrict__ cb, const int* __restrict__ len,
    float* __restrict__ energy, float* __restrict__ partials) {
  const int b = blockIdx.x >> 5;
  const int sp = blockIdx.x & (SPL - 1);
  const int lane = threadIdx.x & 63;
  const int wave = threadIdx.x >> 6;
  const int tid = threadIdx.x;
  const int lb = (b == 0) ? T : len[b];

  __shared__ float s_ctx[4][H];
  __shared__ float s_ml[4][2];

  const int h0 = lane * 4;
  float m = -__builtin_huge_valf();
  float lsum = 0.f;
  float4 acc0 = {0.f, 0.f, 0.f, 0.f};
  float4 acc1 = {0.f, 0.f, 0.f, 0.f};

  const int start = sp * RPB + wave * RPW;
  const int end = min(start + RPW, lb);

  if (start < end) {
    const float4 q0 = *(const float4*)(wq + b * H + h0);
    const float4 q1 = *(const float4*)(wq + b * H + 256 + h0);
    const float c = cb[b];
    const float* Lr = L + ((size_t)b * T + start) * H;
    int r = start;
    // main loop: 4 rows per iteration, 4 independent reduce chains
    for (; r + 3 < end; r += 4, Lr += 4 * H) {
      const float4 r0a = *(const float4*)(Lr + h0);
      const float4 r0b = *(const float4*)(Lr + 256 + h0);
      const float4 r1a = *(const float4*)(Lr + H + h0);
      const float4 r1b = *(const float4*)(Lr + H + 256 + h0);
      const float4 r2a = *(const float4*)(Lr + 2 * H + h0);
      const float4 r2b = *(const float4*)(Lr + 2 * H + 256 + h0);
      const float4 r3a = *(const float4*)(Lr + 3 * H + h0);
      const float4 r3b = *(const float4*)(Lr + 3 * H + 256 + h0);
      float d0 = r0a.x * q0.x + r0a.y * q0.y + r0a.z * q0.z + r0a.w * q0.w +
                 r0b.x * q1.x + r0b.y * q1.y + r0b.z * q1.z + r0b.w * q1.w;
      float d1 = r1a.x * q0.x + r1a.y * q0.y + r1a.z * q0.z + r1a.w * q0.w +
                 r1b.x * q1.x + r1b.y * q1.y + r1b.z * q1.z + r1b.w * q1.w;
      float d2 = r2a.x * q0.x + r2a.y * q0.y + r2a.z * q0.z + r2a.w * q0.w +
                 r2b.x * q1.x + r2b.y * q1.y + r2b.z * q1.z + r2b.w * q1.w;
      float d3 = r3a.x * q0.x + r3a.y * q0.y + r3a.z * q0.z + r3a.w * q0.w +
                 r3b.x * q1.x + r3b.y * q1.y + r3b.z * q1.z + r3b.w * q1.w;
      #pragma unroll
      for (int off = 32; off > 0; off >>= 1) {
        d0 += __shfl_xor(d0, off);
        d1 += __shfl_xor(d1, off);
        d2 += __shfl_xor(d2, off);
        d3 += __shfl_xor(d3, off);
      }
      const float e0 = d0 + c;
      const float e1 = d1 + c;
      const float e2 = d2 + c;
      const float e3 = d3 + c;
      if (lane == 0) {  // one aligned 16B store per 4 rows (r % 4 == 0)
        *(float4*)(energy + b * T + r) = make_float4(e0, e1, e2, e3);
      }
      const float mx = fmaxf(fmaxf(e0, e1), fmaxf(e2, e3));
      const float mn = fmaxf(m, mx);
      const float s = __expf(m - mn);  // ==1 when m unchanged
      const float w0 = __expf(e0 - mn);
      const float w1 = __expf(e1 - mn);
      const float w2 = __expf(e2 - mn);
      const float w3 = __expf(e3 - mn);
      m = mn;
      lsum = lsum * s + ((w0 + w1) + (w2 + w3));
      acc0.x = acc0.x * s + ((w0 * r0a.x + w1 * r1a.x) + (w2 * r2a.x + w3 * r3a.x));
      acc0.y = acc0.y * s + ((w0 * r0a.y + w1 * r1a.y) + (w2 * r2a.y + w3 * r3a.y));
      acc0.z = acc0.z * s + ((w0 * r0a.z + w1 * r1a.z) + (w2 * r2a.z + w3 * r3a.z));
      acc0.w = acc0.w * s + ((w0 * r0a.w + w1 * r1a.w) + (w2 * r2a.w + w3 * r3a.w));
      acc1.x = acc1.x * s + ((w0 * r0b.x + w1 * r1b.x) + (w2 * r2b.x + w3 * r3b.x));
      acc1.y = acc1.y * s + ((w0 * r0b.y + w1 * r1b.y) + (w2 * r2b.y + w3 * r3b.y));
      acc1.z = acc1.z * s + ((w0 * r0b.z + w1 * r1b.z) + (w2 * r2b.z + w3 * r3b.z));
      acc1.w = acc1.w * s + ((w0 * r0b.w + w1 * r1b.w) + (w2 * r2b.w + w3 * r3b.w));
    }
    // tail rows (0-3)
    for (; r < end; ++r, Lr += H) {
      const float4 a0 = *(const float4*)(Lr + h0);
      const float4 a1 = *(const float4*)(Lr + 256 + h0);
      float d = a0.x * q0.x + a0.y * q0.y + a0.z * q0.z + a0.w * q0.w +
                a1.x * q1.x + a1.y * q1.y + a1.z * q1.z + a1.w * q1.w;
      #pragma unroll
      for (int off = 32; off > 0; off >>= 1) d += __shfl_xor(d, off);
      const float e = d + c;
      if (lane == 0) energy[b * T + r] = e;
      const float mn = fmaxf(m, e);
      const float s = __expf(m - mn);
      const float w = __expf(e - mn);
      m = mn;
      lsum = lsum * s + w;
      acc0.x = acc0.x * s + w * a0.x;
      acc0.y = acc0.y * s + w * a0.y;
      acc0.z = acc0.z * s + w * a0.z;
      acc0.w = acc0.w * s + w * a0.w;
      acc1.x = acc1.x * s + w * a1.x;
      acc1.y = acc1.y * s + w * a1.y;
      acc1.z = acc1.z * s + w * a1.z;
      acc1.w = acc1.w * s + w * a1.w;
    }
  }

  if (lane == 0) { s_ml[wave][0] = m; s_ml[wave][1] = lsum; }
  *(float4*)&s_ctx[wave][h0] = acc0;
  *(float4*)&s_ctx[wave][256 + h0] = acc1;
  __syncthreads();

  const float M = fmaxf(fmaxf(s_ml[0][0], s_ml[1][0]),
                        fmaxf(s_ml[2][0], s_ml[3][0]));
  float sc[4], ltot = 0.f;
  #pragma unroll
  for (int w = 0; w < 4; w++) {
    sc[w] = (s_ml[w][0] > -1e38f) ? __expf(s_ml[w][0] - M) : 0.f;
    ltot += s_ml[w][1] * sc[w];
  }
  float v0 = 0.f, v1 = 0.f;
  #pragma unroll
  for (int w = 0; w < 4; w++) {
    v0 += s_ctx[w][tid * 2] * sc[w];
    v1 += s_ctx[w][tid * 2 + 1] * sc[w];
  }
  float* part = partials + (size_t)blockIdx.x * PSTRIDE;
  *(float2*)(part + tid * 2) = make_float2(v0, v1);
  if (tid == 0) { part[512] = M; part[513] = ltot; }
}

// ---------------------------------------------------------------------------
// Kernel C: combine SPL split-partials per batch, Wv GEMV, AND write att row.
// ---------------------------------------------------------------------------
__global__ __launch_bounds__(256) void combine_kernel(
    const float* __restrict__ partials, const float* __restrict__ Wv,
    const float* __restrict__ bv, const float* __restrict__ energy,
    const int* __restrict__ len, float* __restrict__ ctx_out,
    float* __restrict__ att) {
  const int b = blockIdx.x;
  const int tid = threadIdx.x;
  __shared__ float s_ml[SPL][2];
  __shared__ float s_ctx[H];

  if (tid < SPL) {
    const float* p = partials + (size_t)(b * SPL + tid) * PSTRIDE;
    s_ml[tid][0] = p[512];
    s_ml[tid][1] = p[513];
  }
  __syncthreads();

  float M = -__builtin_huge_valf();
  #pragma unroll
  for (int sp = 0; sp < SPL; sp++) M = fmaxf(M, s_ml[sp][0]);
  float ltot = 0.f;
  #pragma unroll
  for (int sp = 0; sp < SPL; sp++) {
    const float s = (s_ml[sp][0] > -1e38f) ? __expf(s_ml[sp][0] - M) : 0.f;
    ltot += s_ml[sp][1] * s;
  }
  const float inv = 1.0f / fmaxf(ltot, 1e-12f);

  float v0 = 0.f, v1 = 0.f;
  #pragma unroll 4
  for (int sp = 0; sp < SPL; sp++) {
    const float s = (s_ml[sp][0] > -1e38f) ? __expf(s_ml[sp][0] - M) : 0.f;
    const float* p = partials + (size_t)(b * SPL + sp) * PSTRIDE;
    v0 += p[tid * 2] * s;
    v1 += p[tid * 2 + 1] * s;
  }
  s_ctx[tid * 2] = v0 * inv;
  s_ctx[tid * 2 + 1] = v1 * inv;
  __syncthreads();

  // attention row: att[b,t] = (t < lb) ? exp(e - M) * inv : 0
  const int lb = (b == 0) ? T : len[b];
  #pragma unroll
  for (int i = 0; i < 8; i++) {
    const int t = tid + 256 * i;
    const float e = (t < lb) ? energy[b * T + t] : M;
    att[b * T + t] = (t < lb) ? __expf(e - M) * inv : 0.f;
  }

  if (tid < V) {
    const float* w = Wv + (size_t)tid * H;
    float a0 = bv[tid], a1 = 0.f, a2 = 0.f, a3 = 0.f;
    for (int h = 0; h < H; h += 16) {
      a0 += w[h]      * s_ctx[h]      + w[h + 1]  * s_ctx[h + 1] +
            w[h + 2]  * s_ctx[h + 2]  + w[h + 3]  * s_ctx[h + 3];
      a1 += w[h + 4]  * s_ctx[h + 4]  + w[h + 5]  * s_ctx[h + 5] +
            w[h + 6]  * s_ctx[h + 6]  + w[h + 7]  * s_ctx[h + 7];
      a2 += w[h + 8]  * s_ctx[h + 8]  + w[h + 9]  * s_ctx[h + 9] +
            w[h + 10] * s_ctx[h + 10] + w[h + 11] * s_ctx[h + 11];
      a3 += w[h + 12] * s_ctx[h + 12] + w[h + 13] * s_ctx[h + 13] +
            w[h + 14] * s_ctx[h + 14] + w[h + 15] * s_ctx[h + 15];
    }
    ctx_out[b * V + tid] = (a0 + a1) + (a2 + a3);
  }
}

extern "C" void kernel_launch(void* const* d_in, const int* in_sizes, int n_in,
                              void* d_out, int out_size, void* d_ws,
                              size_t ws_size, hipStream_t stream) {
  const float* dec = (const float*)d_in[0];   // (B,S)
  const float* L   = (const float*)d_in[1];   // (B,T,H)
  const int*   len = (const int*)d_in[2];     // (B,)
  const float* Ws  = (const float*)d_in[3];   // (K,S)
  const float* bs  = (const float*)d_in[4];   // (K,)
  const float* Wh  = (const float*)d_in[5];   // (K,H)
  const float* bh  = (const float*)d_in[6];   // (K,)
  const float* Wv  = (const float*)d_in[7];   // (V,H)
  const float* bv  = (const float*)d_in[8];   // (V,)

  float* ctx_out = (float*)d_out;             // (B,V)
  float* att_out = (float*)d_out + B * V;     // (B,1,T)

  // workspace layout (floats):
  float* ws = (float*)d_ws;
  float* wq = ws;                               // B*H   = 32768
  float* cb = wq + B * H;                       // B     = 64
  float* energy = cb + B;                       // B*T   = 131072
  float* partials = energy + B * T;             // B*SPL*PSTRIDE = 1056768

  prep_kernel<<<B, 256, 0, stream>>>(dec, Ws, bs, Wh, bh, wq, cb);
  fused_kernel<<<B * SPL, 256, 0, stream>>>(L, wq, cb, len, energy, partials);
  combine_kernel<<<B, 256, 0, stream>>>(partials, Wv, bv, energy, len,
                                        ctx_out, att_out);
}